// Round 3
// baseline (477.524 us; speedup 1.0000x reference)
//
#include <hip/hip_runtime.h>
#include <hip/hip_bf16.h>
#include <cstdint>
#include <cstddef>

#define HD 512
#define BB 64
#define SS 2048
#define VV 32000
#define MM (SS*BB)

typedef __attribute__((ext_vector_type(8))) short bf16x8;
typedef __attribute__((ext_vector_type(4))) float f32x4;

static __device__ __forceinline__ unsigned short f2bf(float f) {
    union { float f; unsigned u; } x; x.f = f;
    unsigned r = x.u + 0x7fffu + ((x.u >> 16) & 1u);
    return (unsigned short)(r >> 16);
}
static __device__ __forceinline__ unsigned pack2(float a, float b) {
    return (unsigned)f2bf(a) | ((unsigned)f2bf(b) << 16);
}
static __device__ __forceinline__ float tanh_fast(float x) {
    float e = __expf(2.f * x);
    return 1.f - 2.f / (e + 1.f);
}
static __device__ __forceinline__ float sigmoid_fast(float x) {
    return 1.f / (1.f + __expf(-x));
}
static __device__ __forceinline__ void gload16(const void* g, void* l) {
    __builtin_amdgcn_global_load_lds(
        (const __attribute__((address_space(1))) void*)g,
        (__attribute__((address_space(3))) void*)l, 16, 0, 0);
}

// ---------------------------------------------------------------------------
// prep: qc[b][n] = hid[b]·Wa[n] + attn_b[n];  WeB = bf16(attn_W[:, H:])
__global__ void prep_kernel(const float* __restrict__ hid,
                            const float* __restrict__ attn_W,
                            const float* __restrict__ attn_b,
                            float* __restrict__ qc,
                            uint4* __restrict__ WeB4) {
    int i = blockIdx.x * 256 + threadIdx.x;      // 0..32767
    int n = i >> 6, b = i & 63;
    const float* hrow = hid + b * HD;
    const float* wrow = attn_W + (size_t)n * (2 * HD);
    float acc = 0.f;
    for (int k = 0; k < HD; k += 4) {
        float4 h4 = *(const float4*)(hrow + k);
        float4 w4 = *(const float4*)(wrow + k);
        acc += h4.x * w4.x + h4.y * w4.y + h4.z * w4.z + h4.w * w4.w;
    }
    qc[b * HD + n] = acc + attn_b[n];
    int col = (i << 3) & 511;
    const float* src = attn_W + (size_t)n * (2 * HD) + HD + col;
    float4 f0 = *(const float4*)(src);
    float4 f1 = *(const float4*)(src + 4);
    uint4 p;
    p.x = pack2(f0.x, f0.y); p.y = pack2(f0.z, f0.w);
    p.z = pack2(f1.x, f1.y); p.w = pack2(f1.z, f1.w);
    WeB4[n * 64 + (col >> 3)] = p;
}

// ---------------------------------------------------------------------------
// scores: BM=128, BN=512, BK=64, 512 thr. Double-buffered B via gload_lds,
// A reg-prefetch, raw barriers + counted vmcnt (T3/T4).
__global__ __launch_bounds__(512, 2) void scores_kernel(
    const float* __restrict__ enc,      // (M, 512) f32
    const uint4* __restrict__ WeB4,     // (512, 512) bf16, 16B chunks
    const float* __restrict__ qc,       // (64, 512)
    const float* __restrict__ vvec,     // (512)
    float* __restrict__ scores)         // (M)
{
    __shared__ uint4 Ald[128 * 8];      // 16 KB
    __shared__ uint4 Bld[2][512 * 8];   // 128 KB
    __shared__ float red[128][8];       // 4 KB

    const int tid = threadIdx.x;
    const int wv = tid >> 6, lane = tid & 63, l15 = lane & 15, l4 = lane >> 4;
    const int m0 = blockIdx.x * 128;

    f32x4 acc[8][4] = {};

    const int ar = tid >> 3;            // 0..63
    const int ac8 = tid & 7;
    const float* ap0 = enc + (size_t)(m0 + ar) * HD + ac8 * 8;
    const float* ap1 = enc + (size_t)(m0 + 64 + ar) * HD + ac8 * 8;
    const int asl0 = ar * 8 + (ac8 ^ (ar & 7));
    const int asl1 = (64 + ar) * 8 + (ac8 ^ (ar & 7));

    const int brow = wv * 8 + (lane >> 3);
    const int bchunk = (lane & 7) ^ (lane >> 3);
    const char* bg = (const char*)WeB4 + ((size_t)brow * 64 + bchunk) * 16;

    float4 pa[2][4];
    // prologue: A(0) regs, B(0) -> Bld[0]
    pa[0][0] = *(const float4*)(ap0);
    pa[0][1] = *(const float4*)(ap0 + 4);
    pa[0][2] = *(const float4*)(ap1);
    pa[0][3] = *(const float4*)(ap1 + 4);
#pragma unroll
    for (int i = 0; i < 8; ++i)
        gload16(bg + (size_t)i * 65536, &Bld[0][i * 512 + tid]);

#pragma unroll
    for (int t = 0; t < 8; ++t) {
        const int cur = t & 1;
        if (t < 7) {
            const int k1 = (t + 1) * 64;
            pa[cur ^ 1][0] = *(const float4*)(ap0 + k1);
            pa[cur ^ 1][1] = *(const float4*)(ap0 + k1 + 4);
            pa[cur ^ 1][2] = *(const float4*)(ap1 + k1);
            pa[cur ^ 1][3] = *(const float4*)(ap1 + k1 + 4);
#pragma unroll
            for (int i = 0; i < 8; ++i)
                gload16(bg + (size_t)i * 65536 + (size_t)k1 * 2,
                        &Bld[cur ^ 1][i * 512 + tid]);
        }
        // pack A(t) -> Ald (compiler auto-waits on pa[cur] loads)
        uint4 u0, u1;
        u0.x = pack2(pa[cur][0].x, pa[cur][0].y);
        u0.y = pack2(pa[cur][0].z, pa[cur][0].w);
        u0.z = pack2(pa[cur][1].x, pa[cur][1].y);
        u0.w = pack2(pa[cur][1].z, pa[cur][1].w);
        u1.x = pack2(pa[cur][2].x, pa[cur][2].y);
        u1.y = pack2(pa[cur][2].z, pa[cur][2].w);
        u1.z = pack2(pa[cur][3].x, pa[cur][3].y);
        u1.w = pack2(pa[cur][3].z, pa[cur][3].w);
        Ald[asl0] = u0;
        Ald[asl1] = u1;
        asm volatile("s_waitcnt lgkmcnt(0)" ::: "memory");
        __builtin_amdgcn_s_barrier();
        if (t < 7) { asm volatile("s_waitcnt vmcnt(12)" ::: "memory"); }
        else       { asm volatile("s_waitcnt vmcnt(0)" ::: "memory"); }
        __builtin_amdgcn_sched_barrier(0);

#pragma unroll
        for (int ks = 0; ks < 2; ++ks) {
            const int chunk = ks * 4 + l4;
            bf16x8 af[8], bfr[4];
#pragma unroll
            for (int mi = 0; mi < 8; ++mi) {
                int row = mi * 16 + l15;
                af[mi] = *(const bf16x8*)&Ald[row * 8 + (chunk ^ (row & 7))];
            }
#pragma unroll
            for (int ni = 0; ni < 4; ++ni) {
                int row = wv * 64 + ni * 16 + l15;
                bfr[ni] = *(const bf16x8*)&Bld[cur][row * 8 + (chunk ^ (row & 7))];
            }
#pragma unroll
            for (int mi = 0; mi < 8; ++mi)
#pragma unroll
                for (int ni = 0; ni < 4; ++ni)
                    acc[mi][ni] = __builtin_amdgcn_mfma_f32_16x16x32_bf16(
                        af[mi], bfr[ni], acc[mi][ni], 0, 0, 0);
        }
        __builtin_amdgcn_s_barrier();
    }

    // epilogue: tanh + dot v, reduce
    float vv[4];
#pragma unroll
    for (int ni = 0; ni < 4; ++ni) vv[ni] = vvec[wv * 64 + ni * 16 + l15];
#pragma unroll
    for (int mi = 0; mi < 8; ++mi) {
#pragma unroll
        for (int r = 0; r < 4; ++r) {
            const int rowl = mi * 16 + l4 * 4 + r;   // 0..127
            float s = 0.f;
#pragma unroll
            for (int ni = 0; ni < 4; ++ni) {
                int n = wv * 64 + ni * 16 + l15;
                float e = acc[mi][ni][r] + qc[(rowl & 63) * HD + n];
                s += tanh_fast(e) * vv[ni];
            }
#pragma unroll
            for (int msk = 8; msk >= 1; msk >>= 1)
                s += __shfl_xor(s, msk);
            if (l15 == 0) red[rowl][wv] = s;
        }
    }
    __syncthreads();
    if (tid < 128) {
        float t = 0.f;
#pragma unroll
        for (int w = 0; w < 8; ++w) t += red[tid][w];
        scores[m0 + tid] = t;
    }
}

// ---------------------------------------------------------------------------
__global__ void softmax_kernel(float* __restrict__ sc) {
    const int b = blockIdx.x;
    const int tid = threadIdx.x;  // 256
    __shared__ float sm[256];
    float m = -1e30f;
    for (int s = tid; s < SS; s += 256) m = fmaxf(m, sc[s * BB + b]);
    sm[tid] = m; __syncthreads();
    for (int o = 128; o > 0; o >>= 1) {
        if (tid < o) sm[tid] = fmaxf(sm[tid], sm[tid + o]);
        __syncthreads();
    }
    m = sm[0]; __syncthreads();
    float sum = 0.f;
    for (int s = tid; s < SS; s += 256) {
        float e = __expf(sc[s * BB + b] - m);
        sc[s * BB + b] = e;
        sum += e;
    }
    sm[tid] = sum; __syncthreads();
    for (int o = 128; o > 0; o >>= 1) {
        if (tid < o) sm[tid] += sm[tid + o];
        __syncthreads();
    }
    float inv = 1.f / sm[0];
    for (int s = tid; s < SS; s += 256) sc[s * BB + b] *= inv;
}

// ---------------------------------------------------------------------------
__global__ void ctx_kernel(const float* __restrict__ enc,
                           const float* __restrict__ attn,
                           float* __restrict__ part) {
    const int b = blockIdx.x & 63;
    const int chunk = blockIdx.x >> 6;       // 0..15
    const int h0 = threadIdx.x * 4;          // 128 thr
    float4 a = {0.f, 0.f, 0.f, 0.f};
    const int sbase = chunk * 128;
#pragma unroll 4
    for (int si = 0; si < 128; ++si) {
        int s = sbase + si;
        float w = attn[s * BB + b];
        float4 e = *(const float4*)(enc + (size_t)(s * BB + b) * HD + h0);
        a.x += w * e.x; a.y += w * e.y; a.z += w * e.z; a.w += w * e.w;
    }
    *(float4*)(part + (size_t)(chunk * BB + b) * HD + h0) = a;
}

__global__ void gather_reduce_kernel(const float* __restrict__ part,
                                     const int* __restrict__ word,
                                     const float* __restrict__ emb,
                                     float* __restrict__ x,
                                     unsigned* __restrict__ y_bf) {
    const int b = blockIdx.x;
    const int h0 = threadIdx.x * 4;          // 128 thr
    float4 a = {0.f, 0.f, 0.f, 0.f};
    for (int c = 0; c < 16; ++c) {
        float4 p = *(const float4*)(part + (size_t)(c * BB + b) * HD + h0);
        a.x += p.x; a.y += p.y; a.z += p.z; a.w += p.w;
    }
    *(float4*)(x + b * 1024 + HD + h0) = a;
    uint2 u; u.x = pack2(a.x, a.y); u.y = pack2(a.z, a.w);
    *(uint2*)(y_bf + b * 512 + 256 + (h0 >> 1)) = u;
    int w = word[b];
    float4 e = *(const float4*)(emb + (size_t)w * HD + h0);
    *(float4*)(x + b * 1024 + h0) = e;
}

// ---------------------------------------------------------------------------
__global__ void gates_kernel(const float* __restrict__ x,
                             const float* __restrict__ hid,
                             const float* __restrict__ W_ih,
                             const float* __restrict__ W_hh,
                             const float* __restrict__ b_ih,
                             const float* __restrict__ b_hh,
                             float* __restrict__ gi, float* __restrict__ gh) {
    const int tid = threadIdx.x;
    const int b = tid & 63;
    const int j = blockIdx.x * 4 + (tid >> 6);
    float agi = 0.f, agh = 0.f;
    const float* xr = x + b * 1024;
    const float* wr = W_ih + (size_t)j * 1024;
    for (int k = 0; k < 1024; k += 4) {
        float4 xv = *(const float4*)(xr + k);
        float4 w4 = *(const float4*)(wr + k);
        agi += xv.x * w4.x + xv.y * w4.y + xv.z * w4.z + xv.w * w4.w;
    }
    const float* hr = hid + b * HD;
    const float* wh = W_hh + (size_t)j * HD;
    for (int k = 0; k < HD; k += 4) {
        float4 hv = *(const float4*)(hr + k);
        float4 w4 = *(const float4*)(wh + k);
        agh += hv.x * w4.x + hv.y * w4.y + hv.z * w4.z + hv.w * w4.w;
    }
    gi[b * 1536 + j] = agi + b_ih[j];
    gh[b * 1536 + j] = agh + b_hh[j];
}

__global__ void hnew_kernel(const float* __restrict__ gi,
                            const float* __restrict__ gh,
                            const float* __restrict__ hid,
                            float* __restrict__ out_h,
                            unsigned* __restrict__ y_bf) {
    const int b = blockIdx.x;
    const int h = threadIdx.x * 2;           // 256 thr
    float hn[2];
#pragma unroll
    for (int j = 0; j < 2; ++j) {
        int hh = h + j;
        float r = sigmoid_fast(gi[b * 1536 + hh] + gh[b * 1536 + hh]);
        float z = sigmoid_fast(gi[b * 1536 + 512 + hh] + gh[b * 1536 + 512 + hh]);
        float n = tanh_fast(gi[b * 1536 + 1024 + hh] + r * gh[b * 1536 + 1024 + hh]);
        hn[j] = (1.f - z) * n + z * hid[b * HD + hh];
        out_h[b * HD + hh] = hn[j];
    }
    y_bf[b * 512 + (h >> 1)] = pack2(hn[0], hn[1]);
}

// ---------------------------------------------------------------------------
// logits: y staged once in LDS (bf16, 128 KB via gload_lds); W 2-deep
// reg-prefetch -> pack -> 16 KB LDS. 256 thr, BN=128, 16 K-iters.
__global__ __launch_bounds__(256, 2) void logits_kernel(
    const unsigned short* __restrict__ y_bf,  // (64, 1024) bf16
    const float* __restrict__ out_W,          // (V, 1024)
    const float* __restrict__ out_b,
    float* __restrict__ logits)               // (64, V)
{
    __shared__ uint4 Yld[64 * 128];    // 128 KB
    __shared__ uint4 Wld[128 * 8];     // 16 KB
    const int tid = threadIdx.x;
    const int wv = tid >> 6, lane = tid & 63, l15 = lane & 15, l4 = lane >> 4;
    const int n0 = blockIdx.x * 128;

    f32x4 acc[4][2] = {};

    // stage y once: slot s holds chunk (s&127)^(row&7) of row s>>7
#pragma unroll
    for (int i = 0; i < 32; ++i) {
        int s = i * 256 + tid;
        int yr = s >> 7, yc = s & 127;
        gload16(y_bf + ((size_t)yr * 1024 + ((size_t)(yc ^ (yr & 7)) << 3)), &Yld[s]);
    }
    const int wr = tid >> 3, wc8 = tid & 7;
    const float* wp0 = out_W + (size_t)(n0 + wr) * 1024 + wc8 * 8;
    const int wsl = wc8 ^ (wr & 7);
    float4 pw[2][8];
#pragma unroll
    for (int i = 0; i < 4; ++i) {           // W(0)
        pw[0][i * 2]     = *(const float4*)(wp0 + (size_t)i * 32768);
        pw[0][i * 2 + 1] = *(const float4*)(wp0 + (size_t)i * 32768 + 4);
    }
#pragma unroll
    for (int i = 0; i < 4; ++i) {           // W(1)
        pw[1][i * 2]     = *(const float4*)(wp0 + (size_t)i * 32768 + 64);
        pw[1][i * 2 + 1] = *(const float4*)(wp0 + (size_t)i * 32768 + 68);
    }
    asm volatile("s_waitcnt vmcnt(16)" ::: "memory");   // Yld landed; W0/W1 in flight
    __builtin_amdgcn_sched_barrier(0);
    __builtin_amdgcn_s_barrier();

#pragma unroll
    for (int t = 0; t < 16; ++t) {
        const int cur = t & 1;
#pragma unroll
        for (int i = 0; i < 4; ++i) {       // pack W(t) -> Wld
            uint4 u;
            u.x = pack2(pw[cur][i * 2].x, pw[cur][i * 2].y);
            u.y = pack2(pw[cur][i * 2].z, pw[cur][i * 2].w);
            u.z = pack2(pw[cur][i * 2 + 1].x, pw[cur][i * 2 + 1].y);
            u.w = pack2(pw[cur][i * 2 + 1].z, pw[cur][i * 2 + 1].w);
            Wld[(wr + 32 * i) * 8 + wsl] = u;
        }
        if (t < 14) {
            const int k2 = (t + 2) * 64;
#pragma unroll
            for (int i = 0; i < 4; ++i) {   // issue W(t+2)
                pw[cur][i * 2]     = *(const float4*)(wp0 + (size_t)i * 32768 + k2);
                pw[cur][i * 2 + 1] = *(const float4*)(wp0 + (size_t)i * 32768 + k2 + 4);
            }
        }
        asm volatile("s_waitcnt lgkmcnt(0)" ::: "memory");
        __builtin_amdgcn_s_barrier();
#pragma unroll
        for (int ks = 0; ks < 2; ++ks) {
            const int kc = t * 8 + ks * 4 + l4;        // y chunk 0..127
            const int wc = ks * 4 + l4;                // W chunk 0..7
            bf16x8 af[4], bfr[2];
#pragma unroll
            for (int mi = 0; mi < 4; ++mi) {
                int row = mi * 16 + l15;
                af[mi] = *(const bf16x8*)&Yld[row * 128 + (kc ^ (row & 7))];
            }
#pragma unroll
            for (int ni = 0; ni < 2; ++ni) {
                int row = wv * 32 + ni * 16 + l15;
                bfr[ni] = *(const bf16x8*)&Wld[row * 8 + (wc ^ (row & 7))];
            }
#pragma unroll
            for (int mi = 0; mi < 4; ++mi)
#pragma unroll
                for (int ni = 0; ni < 2; ++ni)
                    acc[mi][ni] = __builtin_amdgcn_mfma_f32_16x16x32_bf16(
                        af[mi], bfr[ni], acc[mi][ni], 0, 0, 0);
        }
        __builtin_amdgcn_s_barrier();
    }
#pragma unroll
    for (int mi = 0; mi < 4; ++mi) {
#pragma unroll
        for (int r = 0; r < 4; ++r) {
            const int b = mi * 16 + l4 * 4 + r;
#pragma unroll
            for (int ni = 0; ni < 2; ++ni) {
                int n = n0 + wv * 32 + ni * 16 + l15;
                logits[(size_t)b * VV + n] = acc[mi][ni][r] + out_b[n];
            }
        }
    }
}

// log_softmax in place over each row of (64, 32000)
__global__ void lsm_kernel(float* __restrict__ logits) {
    const int b = blockIdx.x;
    const int tid = threadIdx.x;  // 1024
    __shared__ float sm[1024];
    float* row = logits + (size_t)b * VV;
    float m = -1e30f;
    for (int i = tid; i < VV; i += 1024) m = fmaxf(m, row[i]);
    sm[tid] = m; __syncthreads();
    for (int o = 512; o > 0; o >>= 1) {
        if (tid < o) sm[tid] = fmaxf(sm[tid], sm[tid + o]);
        __syncthreads();
    }
    m = sm[0]; __syncthreads();
    float s = 0.f;
    for (int i = tid; i < VV; i += 1024) s += __expf(row[i] - m);
    sm[tid] = s; __syncthreads();
    for (int o = 512; o > 0; o >>= 1) {
        if (tid < o) sm[tid] += sm[tid + o];
        __syncthreads();
    }
    float lse = m + __logf(sm[0]);
    for (int i = tid; i < VV; i += 1024) row[i] -= lse;
}

// ---------------------------------------------------------------------------
extern "C" void kernel_launch(void* const* d_in, const int* in_sizes, int n_in,
                              void* d_out, int out_size, void* d_ws, size_t ws_size,
                              hipStream_t stream) {
    (void)in_sizes; (void)n_in; (void)out_size; (void)ws_size;
    const int*   word   = (const int*)d_in[0];
    const float* hid    = (const float*)d_in[1];
    const float* enc    = (const float*)d_in[2];
    const float* emb    = (const float*)d_in[3];
    const float* attn_W = (const float*)d_in[4];
    const float* attn_b = (const float*)d_in[5];
    const float* v      = (const float*)d_in[6];
    const float* W_ih   = (const float*)d_in[7];
    const float* W_hh   = (const float*)d_in[8];
    const float* b_ih   = (const float*)d_in[9];
    const float* b_hh   = (const float*)d_in[10];
    const float* out_W  = (const float*)d_in[11];
    const float* out_b  = (const float*)d_in[12];

    float* out    = (float*)d_out;
    float* logits = out;                         // (B, V)
    float* out_h  = out + (size_t)BB * VV;       // (B, H)

    char* ws = (char*)d_ws;
    float* qc      = (float*)ws;    ws += 64 * 512 * 4;
    uint4* WeB4    = (uint4*)ws;    ws += 512 * 512 * 2;
    float* sc      = (float*)ws;    ws += MM * 4;
    float* part    = (float*)ws;    ws += 16 * 64 * 512 * 4;
    float* x       = (float*)ws;    ws += 64 * 1024 * 4;
    unsigned* y_bf = (unsigned*)ws; ws += 64 * 1024 * 2;
    float* gi      = (float*)ws;    ws += 64 * 1536 * 4;
    float* gh      = (float*)ws;    ws += 64 * 1536 * 4;

    prep_kernel<<<128, 256, 0, stream>>>(hid, attn_W, attn_b, qc, WeB4);
    scores_kernel<<<MM / 128, 512, 0, stream>>>(enc, WeB4, qc, v, sc);
    softmax_kernel<<<BB, 256, 0, stream>>>(sc);
    ctx_kernel<<<16 * BB, 128, 0, stream>>>(enc, sc, part);
    gather_reduce_kernel<<<BB, 128, 0, stream>>>(part, word, emb, x, y_bf);
    gates_kernel<<<384, 256, 0, stream>>>(x, hid, W_ih, W_hh, b_ih, b_hh, gi, gh);
    hnew_kernel<<<BB, 256, 0, stream>>>(gi, gh, hid, out_h, y_bf);
    logits_kernel<<<VV / 128, 256, 0, stream>>>((const unsigned short*)y_bf, out_W, out_b, logits);
    lsm_kernel<<<BB, 1024, 0, stream>>>(logits);
}

// Round 4
// 435.371 us; speedup vs baseline: 1.0968x; 1.0968x over previous
//
#include <hip/hip_runtime.h>
#include <hip/hip_bf16.h>
#include <cstdint>
#include <cstddef>

#define HD 512
#define BB 64
#define SS 2048
#define VV 32000
#define MM (SS*BB)

typedef __attribute__((ext_vector_type(8))) short bf16x8;
typedef __attribute__((ext_vector_type(4))) float f32x4;

static __device__ __forceinline__ unsigned short f2bf(float f) {
    union { float f; unsigned u; } x; x.f = f;
    unsigned r = x.u + 0x7fffu + ((x.u >> 16) & 1u);
    return (unsigned short)(r >> 16);
}
static __device__ __forceinline__ unsigned pack2(float a, float b) {
    return (unsigned)f2bf(a) | ((unsigned)f2bf(b) << 16);
}
static __device__ __forceinline__ float tanh_fast(float x) {
    float e = __expf(2.f * x);
    return 1.f - 2.f / (e + 1.f);
}
static __device__ __forceinline__ float sigmoid_fast(float x) {
    return 1.f / (1.f + __expf(-x));
}
static __device__ __forceinline__ void gload16(const void* g, void* l) {
    __builtin_amdgcn_global_load_lds(
        (const __attribute__((address_space(1))) void*)g,
        (__attribute__((address_space(3))) void*)l, 16, 0, 0);
}

// ---------------------------------------------------------------------------
// prep: qc[b][n] = hid[b]·Wa[n] + attn_b[n];  WeB = bf16(attn_W[:, H:])
__global__ void prep_kernel(const float* __restrict__ hid,
                            const float* __restrict__ attn_W,
                            const float* __restrict__ attn_b,
                            float* __restrict__ qc,
                            uint4* __restrict__ WeB4) {
    int i = blockIdx.x * 256 + threadIdx.x;      // 0..32767
    int n = i >> 6, b = i & 63;
    const float* hrow = hid + b * HD;
    const float* wrow = attn_W + (size_t)n * (2 * HD);
    float acc = 0.f;
    for (int k = 0; k < HD; k += 4) {
        float4 h4 = *(const float4*)(hrow + k);
        float4 w4 = *(const float4*)(wrow + k);
        acc += h4.x * w4.x + h4.y * w4.y + h4.z * w4.z + h4.w * w4.w;
    }
    qc[b * HD + n] = acc + attn_b[n];
    int col = (i << 3) & 511;
    const float* src = attn_W + (size_t)n * (2 * HD) + HD + col;
    float4 f0 = *(const float4*)(src);
    float4 f1 = *(const float4*)(src + 4);
    uint4 p;
    p.x = pack2(f0.x, f0.y); p.y = pack2(f0.z, f0.w);
    p.z = pack2(f1.x, f1.y); p.w = pack2(f1.z, f1.w);
    WeB4[n * 64 + (col >> 3)] = p;
}

// ---------------------------------------------------------------------------
// scores partial: scp[m][nh] = sum_{n in nh-range} tanh(E[m,n]+qc[b,n])*v[n]
// BM=64, BN=128, BK=32, 256 thr (4 waves), grid = 2048 m-tiles x 4 nh.
// Simple drain-per-iter loop; latency hidden by ~6 blocks/CU.
__global__ __launch_bounds__(256, 6) void scores_kernel(
    const float* __restrict__ enc,      // (M, 512) f32
    const uint4* __restrict__ WeB4,     // (512 rows x 64 chunks) bf16
    const float* __restrict__ qc,       // (64, 512)
    const float* __restrict__ vvec,     // (512)
    float* __restrict__ scp)            // (M, 4) partials
{
    __shared__ uint4 Ald[256];          // 4 KB : 64 rows x 4 chunks
    __shared__ uint4 Bld[512];          // 8 KB : 128 rows x 4 chunks
    __shared__ float red[64][4];        // 1 KB

    const int tid = threadIdx.x;
    const int wv = tid >> 6, lane = tid & 63, l15 = lane & 15, l4 = lane >> 4;
    const int mt = blockIdx.x >> 2, nh = blockIdx.x & 3;
    const int m0 = mt * 64, nb = nh * 128;

    f32x4 acc[4][2] = {};

    // A staging: LDS slot tid <-> row=tid>>2, holds global chunk (tid&3)^(row&3)
    const int arow = tid >> 2;
    const int acc8 = (((tid & 3) ^ (arow & 3))) * 8;
    const float* aptr = enc + (size_t)(m0 + arow) * HD + acc8;

    // B staging (gload16, linear LDS dest): slot i*256+tid, row_l=i*64+wv*16+(lane>>2)
    const int br_sub = wv * 16 + (lane >> 2);
    const int bcc = (lane & 3) ^ ((lane >> 2) & 3);

    for (int t = 0; t < 16; ++t) {
        const int k0 = t * 32;
        __syncthreads();                 // prev iter's ds_reads done
        float4 a0 = *(const float4*)(aptr + k0);
        float4 a1 = *(const float4*)(aptr + k0 + 4);
#pragma unroll
        for (int i = 0; i < 2; ++i) {
            int row_l = i * 64 + br_sub;
            gload16((const char*)WeB4 +
                        ((size_t)(nb + row_l) * 64 + (k0 >> 3) + bcc) * 16,
                    &Bld[i * 256 + tid]);
        }
        uint4 u;
        u.x = pack2(a0.x, a0.y); u.y = pack2(a0.z, a0.w);
        u.z = pack2(a1.x, a1.y); u.w = pack2(a1.z, a1.w);
        Ald[tid] = u;
        __syncthreads();                 // drains vmcnt (B landed) + lgkm (A written)

        bf16x8 af[4], bfr[2];
#pragma unroll
        for (int mi = 0; mi < 4; ++mi) {
            int row = mi * 16 + l15;
            af[mi] = *(const bf16x8*)&Ald[row * 4 + (l4 ^ (row & 3))];
        }
#pragma unroll
        for (int ni = 0; ni < 2; ++ni) {
            int row = wv * 32 + ni * 16 + l15;
            bfr[ni] = *(const bf16x8*)&Bld[row * 4 + (l4 ^ (row & 3))];
        }
#pragma unroll
        for (int mi = 0; mi < 4; ++mi)
#pragma unroll
            for (int ni = 0; ni < 2; ++ni)
                acc[mi][ni] = __builtin_amdgcn_mfma_f32_16x16x32_bf16(
                    af[mi], bfr[ni], acc[mi][ni], 0, 0, 0);
    }

    // epilogue: tanh + dot v over this wave's 32 cols
    float vv[2];
#pragma unroll
    for (int ni = 0; ni < 2; ++ni) vv[ni] = vvec[nb + wv * 32 + ni * 16 + l15];
#pragma unroll
    for (int mi = 0; mi < 4; ++mi) {
#pragma unroll
        for (int r = 0; r < 4; ++r) {
            const int rowl = mi * 16 + l4 * 4 + r;   // 0..63 == b
            float s = 0.f;
#pragma unroll
            for (int ni = 0; ni < 2; ++ni) {
                int n = nb + wv * 32 + ni * 16 + l15;
                float e = acc[mi][ni][r] + qc[rowl * HD + n];
                s += tanh_fast(e) * vv[ni];
            }
#pragma unroll
            for (int msk = 8; msk >= 1; msk >>= 1)
                s += __shfl_xor(s, msk);
            if (l15 == 0) red[rowl][wv] = s;
        }
    }
    __syncthreads();
    if (tid < 64) {
        float t = red[tid][0] + red[tid][1] + red[tid][2] + red[tid][3];
        scp[(size_t)(m0 + tid) * 4 + nh] = t;
    }
}

// ---------------------------------------------------------------------------
// softmax over s for each b: reads 4 partials per (s,b), writes attn to at[]
__global__ void softmax_kernel(const float4* __restrict__ scp,
                               float* __restrict__ at) {
    const int b = blockIdx.x;
    const int tid = threadIdx.x;  // 256
    __shared__ float sm[256];
    __shared__ float row[SS];
    float m = -1e30f;
    for (int s = tid; s < SS; s += 256) {
        float4 p = scp[s * BB + b];
        float val = (p.x + p.y) + (p.z + p.w);
        row[s] = val;
        m = fmaxf(m, val);
    }
    sm[tid] = m; __syncthreads();
    for (int o = 128; o > 0; o >>= 1) {
        if (tid < o) sm[tid] = fmaxf(sm[tid], sm[tid + o]);
        __syncthreads();
    }
    m = sm[0]; __syncthreads();
    float sum = 0.f;
    for (int s = tid; s < SS; s += 256) {
        float e = __expf(row[s] - m);
        row[s] = e;
        sum += e;
    }
    sm[tid] = sum; __syncthreads();
    for (int o = 128; o > 0; o >>= 1) {
        if (tid < o) sm[tid] += sm[tid + o];
        __syncthreads();
    }
    float inv = 1.f / sm[0];
    for (int s = tid; s < SS; s += 256) at[s * BB + b] = row[s] * inv;
}

// ---------------------------------------------------------------------------
__global__ void ctx_kernel(const float* __restrict__ enc,
                           const float* __restrict__ attn,
                           float* __restrict__ part) {
    const int b = blockIdx.x & 63;
    const int chunk = blockIdx.x >> 6;       // 0..15
    const int h0 = threadIdx.x * 4;          // 128 thr
    float4 a = {0.f, 0.f, 0.f, 0.f};
    const int sbase = chunk * 128;
#pragma unroll 4
    for (int si = 0; si < 128; ++si) {
        int s = sbase + si;
        float w = attn[s * BB + b];
        float4 e = *(const float4*)(enc + (size_t)(s * BB + b) * HD + h0);
        a.x += w * e.x; a.y += w * e.y; a.z += w * e.z; a.w += w * e.w;
    }
    *(float4*)(part + (size_t)(chunk * BB + b) * HD + h0) = a;
}

__global__ void gather_reduce_kernel(const float* __restrict__ part,
                                     const int* __restrict__ word,
                                     const float* __restrict__ emb,
                                     float* __restrict__ x,
                                     unsigned* __restrict__ y_bf) {
    const int b = blockIdx.x;
    const int h0 = threadIdx.x * 4;          // 128 thr
    float4 a = {0.f, 0.f, 0.f, 0.f};
    for (int c = 0; c < 16; ++c) {
        float4 p = *(const float4*)(part + (size_t)(c * BB + b) * HD + h0);
        a.x += p.x; a.y += p.y; a.z += p.z; a.w += p.w;
    }
    *(float4*)(x + b * 1024 + HD + h0) = a;
    uint2 u; u.x = pack2(a.x, a.y); u.y = pack2(a.z, a.w);
    *(uint2*)(y_bf + b * 512 + 256 + (h0 >> 1)) = u;
    int w = word[b];
    float4 e = *(const float4*)(emb + (size_t)w * HD + h0);
    *(float4*)(x + b * 1024 + h0) = e;
}

// ---------------------------------------------------------------------------
__global__ void gates_kernel(const float* __restrict__ x,
                             const float* __restrict__ hid,
                             const float* __restrict__ W_ih,
                             const float* __restrict__ W_hh,
                             const float* __restrict__ b_ih,
                             const float* __restrict__ b_hh,
                             float* __restrict__ gi, float* __restrict__ gh) {
    const int tid = threadIdx.x;
    const int b = tid & 63;
    const int j = blockIdx.x * 4 + (tid >> 6);
    float agi = 0.f, agh = 0.f;
    const float* xr = x + b * 1024;
    const float* wr = W_ih + (size_t)j * 1024;
    for (int k = 0; k < 1024; k += 4) {
        float4 xv = *(const float4*)(xr + k);
        float4 w4 = *(const float4*)(wr + k);
        agi += xv.x * w4.x + xv.y * w4.y + xv.z * w4.z + xv.w * w4.w;
    }
    const float* hr = hid + b * HD;
    const float* wh = W_hh + (size_t)j * HD;
    for (int k = 0; k < HD; k += 4) {
        float4 hv = *(const float4*)(hr + k);
        float4 w4 = *(const float4*)(wh + k);
        agh += hv.x * w4.x + hv.y * w4.y + hv.z * w4.z + hv.w * w4.w;
    }
    gi[b * 1536 + j] = agi + b_ih[j];
    gh[b * 1536 + j] = agh + b_hh[j];
}

__global__ void hnew_kernel(const float* __restrict__ gi,
                            const float* __restrict__ gh,
                            const float* __restrict__ hid,
                            float* __restrict__ out_h,
                            unsigned* __restrict__ y_bf) {
    const int b = blockIdx.x;
    const int h = threadIdx.x * 2;           // 256 thr
    float hn[2];
#pragma unroll
    for (int j = 0; j < 2; ++j) {
        int hh = h + j;
        float r = sigmoid_fast(gi[b * 1536 + hh] + gh[b * 1536 + hh]);
        float z = sigmoid_fast(gi[b * 1536 + 512 + hh] + gh[b * 1536 + 512 + hh]);
        float n = tanh_fast(gi[b * 1536 + 1024 + hh] + r * gh[b * 1536 + 1024 + hh]);
        hn[j] = (1.f - z) * n + z * hid[b * HD + hh];
        out_h[b * HD + hh] = hn[j];
    }
    y_bf[b * 512 + (h >> 1)] = pack2(hn[0], hn[1]);
}

// ---------------------------------------------------------------------------
// logits: y staged once in LDS (bf16, 128 KB via gload_lds); W 2-deep
// reg-prefetch -> pack -> 16 KB LDS. 256 thr, BN=128, 16 K-iters.
__global__ __launch_bounds__(256, 2) void logits_kernel(
    const unsigned short* __restrict__ y_bf,  // (64, 1024) bf16
    const float* __restrict__ out_W,          // (V, 1024)
    const float* __restrict__ out_b,
    float* __restrict__ logits)               // (64, V)
{
    __shared__ uint4 Yld[64 * 128];    // 128 KB
    __shared__ uint4 Wld[128 * 8];     // 16 KB
    const int tid = threadIdx.x;
    const int wv = tid >> 6, lane = tid & 63, l15 = lane & 15, l4 = lane >> 4;
    const int n0 = blockIdx.x * 128;

    f32x4 acc[4][2] = {};

    // stage y once: slot s holds chunk (s&127)^(row&7) of row s>>7
#pragma unroll
    for (int i = 0; i < 32; ++i) {
        int s = i * 256 + tid;
        int yr = s >> 7, yc = s & 127;
        gload16(y_bf + ((size_t)yr * 1024 + ((size_t)(yc ^ (yr & 7)) << 3)), &Yld[s]);
    }
    const int wr = tid >> 3, wc8 = tid & 7;
    const float* wp0 = out_W + (size_t)(n0 + wr) * 1024 + wc8 * 8;
    const int wsl = wc8 ^ (wr & 7);
    float4 pw[2][8];
#pragma unroll
    for (int i = 0; i < 4; ++i) {           // W(0)
        pw[0][i * 2]     = *(const float4*)(wp0 + (size_t)i * 32768);
        pw[0][i * 2 + 1] = *(const float4*)(wp0 + (size_t)i * 32768 + 4);
    }
#pragma unroll
    for (int i = 0; i < 4; ++i) {           // W(1)
        pw[1][i * 2]     = *(const float4*)(wp0 + (size_t)i * 32768 + 64);
        pw[1][i * 2 + 1] = *(const float4*)(wp0 + (size_t)i * 32768 + 68);
    }
    asm volatile("s_waitcnt vmcnt(16)" ::: "memory");   // Yld landed; W0/W1 in flight
    __builtin_amdgcn_sched_barrier(0);
    __builtin_amdgcn_s_barrier();

#pragma unroll
    for (int t = 0; t < 16; ++t) {
        const int cur = t & 1;
#pragma unroll
        for (int i = 0; i < 4; ++i) {       // pack W(t) -> Wld
            uint4 u;
            u.x = pack2(pw[cur][i * 2].x, pw[cur][i * 2].y);
            u.y = pack2(pw[cur][i * 2].z, pw[cur][i * 2].w);
            u.z = pack2(pw[cur][i * 2 + 1].x, pw[cur][i * 2 + 1].y);
            u.w = pack2(pw[cur][i * 2 + 1].z, pw[cur][i * 2 + 1].w);
            Wld[(wr + 32 * i) * 8 + wsl] = u;
        }
        if (t < 14) {
            const int k2 = (t + 2) * 64;
#pragma unroll
            for (int i = 0; i < 4; ++i) {   // issue W(t+2)
                pw[cur][i * 2]     = *(const float4*)(wp0 + (size_t)i * 32768 + k2);
                pw[cur][i * 2 + 1] = *(const float4*)(wp0 + (size_t)i * 32768 + k2 + 4);
            }
        }
        asm volatile("s_waitcnt lgkmcnt(0)" ::: "memory");
        __builtin_amdgcn_s_barrier();
#pragma unroll
        for (int ks = 0; ks < 2; ++ks) {
            const int kc = t * 8 + ks * 4 + l4;        // y chunk 0..127
            const int wc = ks * 4 + l4;                // W chunk 0..7
            bf16x8 af[4], bfr[2];
#pragma unroll
            for (int mi = 0; mi < 4; ++mi) {
                int row = mi * 16 + l15;
                af[mi] = *(const bf16x8*)&Yld[row * 128 + (kc ^ (row & 7))];
            }
#pragma unroll
            for (int ni = 0; ni < 2; ++ni) {
                int row = wv * 32 + ni * 16 + l15;
                bfr[ni] = *(const bf16x8*)&Wld[row * 8 + (wc ^ (row & 7))];
            }
#pragma unroll
            for (int mi = 0; mi < 4; ++mi)
#pragma unroll
                for (int ni = 0; ni < 2; ++ni)
                    acc[mi][ni] = __builtin_amdgcn_mfma_f32_16x16x32_bf16(
                        af[mi], bfr[ni], acc[mi][ni], 0, 0, 0);
        }
        __builtin_amdgcn_s_barrier();
    }
#pragma unroll
    for (int mi = 0; mi < 4; ++mi) {
#pragma unroll
        for (int r = 0; r < 4; ++r) {
            const int b = mi * 16 + l4 * 4 + r;
#pragma unroll
            for (int ni = 0; ni < 2; ++ni) {
                int n = n0 + wv * 32 + ni * 16 + l15;
                logits[(size_t)b * VV + n] = acc[mi][ni][r] + out_b[n];
            }
        }
    }
}

// log_softmax in place over each row of (64, 32000)
__global__ void lsm_kernel(float* __restrict__ logits) {
    const int b = blockIdx.x;
    const int tid = threadIdx.x;  // 1024
    __shared__ float sm[1024];
    float* row = logits + (size_t)b * VV;
    float m = -1e30f;
    for (int i = tid; i < VV; i += 1024) m = fmaxf(m, row[i]);
    sm[tid] = m; __syncthreads();
    for (int o = 512; o > 0; o >>= 1) {
        if (tid < o) sm[tid] = fmaxf(sm[tid], sm[tid + o]);
        __syncthreads();
    }
    m = sm[0]; __syncthreads();
    float s = 0.f;
    for (int i = tid; i < VV; i += 1024) s += __expf(row[i] - m);
    sm[tid] = s; __syncthreads();
    for (int o = 512; o > 0; o >>= 1) {
        if (tid < o) sm[tid] += sm[tid + o];
        __syncthreads();
    }
    float lse = m + __logf(sm[0]);
    for (int i = tid; i < VV; i += 1024) row[i] -= lse;
}

// ---------------------------------------------------------------------------
extern "C" void kernel_launch(void* const* d_in, const int* in_sizes, int n_in,
                              void* d_out, int out_size, void* d_ws, size_t ws_size,
                              hipStream_t stream) {
    (void)in_sizes; (void)n_in; (void)out_size; (void)ws_size;
    const int*   word   = (const int*)d_in[0];
    const float* hid    = (const float*)d_in[1];
    const float* enc    = (const float*)d_in[2];
    const float* emb    = (const float*)d_in[3];
    const float* attn_W = (const float*)d_in[4];
    const float* attn_b = (const float*)d_in[5];
    const float* v      = (const float*)d_in[6];
    const float* W_ih   = (const float*)d_in[7];
    const float* W_hh   = (const float*)d_in[8];
    const float* b_ih   = (const float*)d_in[9];
    const float* b_hh   = (const float*)d_in[10];
    const float* out_W  = (const float*)d_in[11];
    const float* out_b  = (const float*)d_in[12];

    float* out    = (float*)d_out;
    float* logits = out;                         // (B, V)
    float* out_h  = out + (size_t)BB * VV;       // (B, H)

    char* ws = (char*)d_ws;
    float* qc      = (float*)ws;    ws += 64 * 512 * 4;
    uint4* WeB4    = (uint4*)ws;    ws += 512 * 512 * 2;
    float* scp     = (float*)ws;    ws += (size_t)MM * 4 * 4;
    float* at      = (float*)ws;    ws += (size_t)MM * 4;
    float* part    = (float*)ws;    ws += 16 * 64 * 512 * 4;
    float* x       = (float*)ws;    ws += 64 * 1024 * 4;
    unsigned* y_bf = (unsigned*)ws; ws += 64 * 1024 * 2;
    float* gi      = (float*)ws;    ws += 64 * 1536 * 4;
    float* gh      = (float*)ws;    ws += 64 * 1536 * 4;

    prep_kernel<<<128, 256, 0, stream>>>(hid, attn_W, attn_b, qc, WeB4);
    scores_kernel<<<(MM / 64) * 4, 256, 0, stream>>>(enc, WeB4, qc, v, scp);
    softmax_kernel<<<BB, 256, 0, stream>>>((const float4*)scp, at);
    ctx_kernel<<<16 * BB, 128, 0, stream>>>(enc, at, part);
    gather_reduce_kernel<<<BB, 128, 0, stream>>>(part, word, emb, x, y_bf);
    gates_kernel<<<384, 256, 0, stream>>>(x, hid, W_ih, W_hh, b_ih, b_hh, gi, gh);
    hnew_kernel<<<BB, 256, 0, stream>>>(gi, gh, hid, out_h, y_bf);
    logits_kernel<<<VV / 128, 256, 0, stream>>>((const unsigned short*)y_bf, out_W, out_b, logits);
    lsm_kernel<<<BB, 1024, 0, stream>>>(logits);
}